// Round 5
// baseline (108.671 us; speedup 1.0000x reference)
//
#include <hip/hip_runtime.h>
#include <math.h>

#define NB 64
#define NN 1024
#define NC 128
#define NK 512

// K1: fp64 dot(x[row,:], w) — one wave per row, float2 per lane, tree reduce.
__global__ __launch_bounds__(256) void score_kernel(
    const float* __restrict__ x, const float* __restrict__ w,
    double* __restrict__ sacc)
{
    const int row  = blockIdx.x * 4 + (threadIdx.x >> 6);   // < NB*NN
    const int lane = threadIdx.x & 63;
    const float2 xv = *(const float2*)(x + (size_t)row * NC + lane * 2);
    const float2 wv = *(const float2*)(w + lane * 2);
    double acc = (double)xv.x * (double)wv.x + (double)xv.y * (double)wv.y;
    #pragma unroll
    for (int off = 32; off > 0; off >>= 1)
        acc += __shfl_xor(acc, off, 64);
    if (lane == 0) sacc[row] = acc;
}

// K2: exact rank-sort top-k on pre-tanh scores (monotone => same order as ref).
__global__ __launch_bounds__(256) void rank_kernel(
    const double* __restrict__ sacc, const float* __restrict__ w,
    int* __restrict__ perm, float* __restrict__ gate, int* __restrict__ inv)
{
    __shared__ double s[NN];
    __shared__ double s_rnw;
    const int b = blockIdx.x >> 2;
    const int q = blockIdx.x & 3;
    const int t = threadIdx.x;
    for (int idx = t; idx < NN; idx += 256)
        s[idx] = sacc[(size_t)b * NN + idx];
    if (t < 64) {
        double p = (double)w[t] * (double)w[t]
                 + (double)w[t + 64] * (double)w[t + 64];
        #pragma unroll
        for (int off = 32; off > 0; off >>= 1)
            p += __shfl_xor(p, off, 64);
        if (t == 0) s_rnw = 1.0 / sqrt(p);
    }
    __syncthreads();

    const int n = q * 256 + t;
    const double my = s[n];
    int r = 0;
    #pragma unroll 8
    for (int j = 0; j < NN; ++j) {
        double o = s[j];
        r += (o > my) || ((o == my) && (j < n));
    }
    inv[b * NN + n] = (r < NK) ? r : -1;
    if (r < NK) {
        perm[b * NK + r] = n;
        gate[b * NK + r] = (float)tanh(my * s_rnw);
    }
}

// K3: fused scan (blocks 0..255) + xpool (blocks 256..1279), 1024 threads.
// Scan: 4 blocks/graph, 128 pooled rows each; forward bits only, LDS bitmap
// [128][17] u32 (pad kills bank conflicts); dump to global COL-MAJOR bitmap
// bm[b][w][j] (w=word-col 0..15, j=pooled row 0..511).
__global__ __launch_bounds__(1024) void scan_xpool_kernel(
    const float* __restrict__ adj, const int* __restrict__ perm,
    const int* __restrict__ inv, const float* __restrict__ gate,
    const float* __restrict__ x, unsigned* __restrict__ bm,
    float* __restrict__ x_pool)
{
    __shared__ unsigned bits[128 * 17];   // 8.5 KB
    __shared__ int sinv[NN];              // 4 KB
    if (blockIdx.x >= 256) {
        // ---- xpool role: x_pool[bi][c] = x[b][perm[bi]][c] * gate[bi]
        int id = (blockIdx.x - 256) * 1024 + threadIdx.x;  // < NB*NK*NC/4
        int c4 = id & (NC / 4 - 1);
        int bi = id >> 5;
        int b  = bi >> 9;
        int pi = perm[bi];
        float g = gate[bi];
        float4 v = *(const float4*)(x + ((size_t)b * NN + pi) * NC + c4 * 4);
        v.x *= g; v.y *= g; v.z *= g; v.w *= g;
        *(float4*)(x_pool + (size_t)id * 4) = v;
        return;
    }
    const int b = blockIdx.x >> 2;
    const int chunk = blockIdx.x & 3;
    const int t = threadIdx.x;
    for (int idx = t; idx < 128 * 17; idx += 1024) bits[idx] = 0;
    for (int idx = t; idx < NN; idx += 1024) sinv[idx] = inv[b * NN + idx];
    __syncthreads();

    const float* ab = adj + (size_t)b * NN * NN;
    const int* permb = perm + b * NK + chunk * 128;
    const int g  = t >> 8;               // local row-group 0..3
    const int lt = t & 255;

    int il = g;                          // local pooled row, stride 4, 32 iters
    int pi = permb[il];
    float4 v = *(const float4*)(ab + (size_t)pi * NN + lt * 4);
    for (int it = 0; it < 32; ++it) {
        int iln = il + 4;
        int pin = 0; float4 vn = v;
        if (it < 31) {                   // 1-deep prefetch
            pin = permb[iln];
            vn = *(const float4*)(ab + (size_t)pin * NN + lt * 4);
        }
        #pragma unroll
        for (int u = 0; u < 4; ++u) {
            if (((const float*)&v)[u] != 0.0f) {
                int j = sinv[lt * 4 + u];
                if (j >= 0)
                    atomicOr(&bits[il * 17 + (j >> 5)], 1u << (j & 31));
            }
        }
        il = iln; pi = pin; v = vn;
    }
    __syncthreads();
    // dump: bm[b*8192 + w*512 + chunk*128 + il] = bits[il*17 + w]
    for (int idx = t; idx < 2048; idx += 1024) {
        int dil = idx & 127, w = idx >> 7;
        bm[(size_t)b * 8192 + w * 512 + chunk * 128 + dil] = bits[dil * 17 + w];
    }
}

// K4: adj_pooled[b,i,j] = (fw(i,j) | trans(j,i)) + (i==j).
// 8 blocks/graph x 64 output rows; stage whole 32 KB graph bitmap (col-major)
// in LDS; fw words copied to padded slab; trans via ds_read_b128.
__global__ __launch_bounds__(256) void adj_write_kernel(
    const unsigned* __restrict__ bm, float* __restrict__ out)
{
    __shared__ unsigned cb[16 * 512];       // 32 KB, cb[w*512 + j]
    __shared__ unsigned fws[64 * 17];       // 4.25 KB padded fw slab
    const int b = blockIdx.x >> 3;
    const int slab = blockIdx.x & 7;        // rows slab*64 .. +63
    const int t = threadIdx.x;
    const uint4* src = (const uint4*)(bm + (size_t)b * 8192);
    for (int idx = t; idx < 2048; idx += 256)
        *(uint4*)&cb[idx * 4] = src[idx];
    __syncthreads();
    for (int idx = t; idx < 64 * 16; idx += 256) {
        int il = idx & 63, wi = idx >> 6;
        fws[il * 17 + wi] = cb[wi * 512 + slab * 64 + il];
    }
    __syncthreads();

    float* ob = out + ((size_t)b * NK + slab * 64) * NK;
    for (int it = 0; it < 32; ++it) {
        int lid = it * 256 + t;             // < 8192
        int i_loc = lid >> 7;               // 0..63
        int i = slab * 64 + i_loc;
        int j4 = (lid & 127) * 4;
        unsigned fw = fws[i_loc * 17 + (j4 >> 5)];
        uint4 tq = *(const uint4*)&cb[(i >> 5) * 512 + j4];
        float4 res;
        float* rp = (float*)&res;
        const unsigned* tp = (const unsigned*)&tq;
        #pragma unroll
        for (int e = 0; e < 4; ++e) {
            unsigned bit = ((fw >> ((j4 + e) & 31)) | (tp[e] >> (i & 31))) & 1u;
            float f = (float)bit;
            if (i == j4 + e) f += 1.0f;
            rp[e] = f;
        }
        *(float4*)(ob + (size_t)i_loc * NK + j4) = res;
    }
}

extern "C" void kernel_launch(void* const* d_in, const int* in_sizes, int n_in,
                              void* d_out, int out_size, void* d_ws, size_t ws_size,
                              hipStream_t stream) {
    const float* x   = (const float*)d_in[0];
    const float* adj = (const float*)d_in[1];
    const float* w   = (const float*)d_in[2];
    float* out = (float*)d_out;

    char* p = (char*)d_ws;
    double*   sacc = (double*)p;    p += sizeof(double) * NB * NN;        // 512 KB
    unsigned* bm   = (unsigned*)p;  p += sizeof(unsigned) * NB * 16 * NK; // 2 MB
    int*      perm = (int*)p;       p += sizeof(int) * NB * NK;           // 128 KB
    float*    gate = (float*)p;     p += sizeof(float) * NB * NK;         // 128 KB
    int*      inv  = (int*)p;                                             // 256 KB

    float* x_pool     = out;                           // NB*NK*NC
    float* adj_pooled = out + (size_t)NB * NK * NC;    // NB*NK*NK

    score_kernel<<<NB * NN / 4, 256, 0, stream>>>(x, w, sacc);
    rank_kernel<<<NB * 4, 256, 0, stream>>>(sacc, w, perm, gate, inv);
    scan_xpool_kernel<<<256 + NB * NK * NC / 4 / 1024, 1024, 0, stream>>>(
        adj, perm, inv, gate, x, bm, x_pool);
    adj_write_kernel<<<NB * 8, 256, 0, stream>>>(bm, adj_pooled);
}

// Round 6
// 96.304 us; speedup vs baseline: 1.1284x; 1.1284x over previous
//
#include <hip/hip_runtime.h>
#include <math.h>

#define NB 64
#define NN 1024
#define NC 128
#define NK 512

// K1: fp64 dot(x[row,:], w) — one wave per row, float2 per lane, tree reduce.
__global__ __launch_bounds__(256) void score_kernel(
    const float* __restrict__ x, const float* __restrict__ w,
    double* __restrict__ sacc)
{
    const int row  = blockIdx.x * 4 + (threadIdx.x >> 6);   // < NB*NN
    const int lane = threadIdx.x & 63;
    const float2 xv = *(const float2*)(x + (size_t)row * NC + lane * 2);
    const float2 wv = *(const float2*)(w + lane * 2);
    double acc = (double)xv.x * (double)wv.x + (double)xv.y * (double)wv.y;
    #pragma unroll
    for (int off = 32; off > 0; off >>= 1)
        acc += __shfl_xor(acc, off, 64);
    if (lane == 0) sacc[row] = acc;
}

// K2: exact rank-sort top-k on pre-tanh scores (monotone => same order as ref).
__global__ __launch_bounds__(256) void rank_kernel(
    const double* __restrict__ sacc, const float* __restrict__ w,
    int* __restrict__ perm, float* __restrict__ gate, int* __restrict__ inv)
{
    __shared__ double s[NN];
    __shared__ double s_rnw;
    const int b = blockIdx.x >> 2;
    const int q = blockIdx.x & 3;
    const int t = threadIdx.x;
    for (int idx = t; idx < NN; idx += 256)
        s[idx] = sacc[(size_t)b * NN + idx];
    if (t < 64) {
        double p = (double)w[t] * (double)w[t]
                 + (double)w[t + 64] * (double)w[t + 64];
        #pragma unroll
        for (int off = 32; off > 0; off >>= 1)
            p += __shfl_xor(p, off, 64);
        if (t == 0) s_rnw = 1.0 / sqrt(p);
    }
    __syncthreads();

    const int n = q * 256 + t;
    const double my = s[n];
    int r = 0;
    #pragma unroll 8
    for (int j = 0; j < NN; ++j) {
        double o = s[j];
        r += (o > my) || ((o == my) && (j < n));
    }
    inv[b * NN + n] = (r < NK) ? r : -1;
    if (r < NK) {
        perm[b * NK + r] = n;
        gate[b * NK + r] = (float)tanh(my * s_rnw);
    }
}

// K3: x_pool[b,i,c] = x[b,perm[b,i],c] * gate[b,i]  (float4)
__global__ void xpool_kernel(
    const float* __restrict__ x, const int* __restrict__ perm,
    const float* __restrict__ gate, float* __restrict__ out)
{
    int id = blockIdx.x * blockDim.x + threadIdx.x;   // < NB*NK*NC/4
    int c4 = id & (NC / 4 - 1);
    int bi = id >> 5;              // b*NK + i
    int b  = bi >> 9;
    int pi = perm[bi];
    float g = gate[bi];
    float4 v = *(const float4*)(x + ((size_t)b * NN + pi) * NC + c4 * 4);
    v.x *= g; v.y *= g; v.z *= g; v.w *= g;
    *(float4*)(out + (size_t)id * 4) = v;
}

// K4: scan — 4 blocks/graph, 128 pooled rows each; forward bits only.
// LDS bitmap [128][17] u32 (pad kills bank conflicts); dump COL-MAJOR to
// bm[b][w][j] (w=word-col 0..15, j=pooled row 0..511).
__global__ __launch_bounds__(1024) void adj_scan_kernel(
    const float* __restrict__ adj, const int* __restrict__ perm,
    const int* __restrict__ inv, unsigned* __restrict__ bm)
{
    __shared__ unsigned bits[128 * 17];   // 8.5 KB
    __shared__ int sinv[NN];              // 4 KB
    const int b = blockIdx.x >> 2;
    const int chunk = blockIdx.x & 3;
    const int t = threadIdx.x;
    for (int idx = t; idx < 128 * 17; idx += 1024) bits[idx] = 0;
    for (int idx = t; idx < NN; idx += 1024) sinv[idx] = inv[b * NN + idx];
    __syncthreads();

    const float* ab = adj + (size_t)b * NN * NN;
    const int* permb = perm + b * NK + chunk * 128;
    const int g  = t >> 8;               // local row-group 0..3
    const int lt = t & 255;

    int il = g;                          // local pooled row, stride 4, 32 iters
    int pi = permb[il];
    float4 v = *(const float4*)(ab + (size_t)pi * NN + lt * 4);
    for (int it = 0; it < 32; ++it) {
        int iln = il + 4;
        int pin = 0; float4 vn = v;
        if (it < 31) {                   // 1-deep prefetch
            pin = permb[iln];
            vn = *(const float4*)(ab + (size_t)pin * NN + lt * 4);
        }
        #pragma unroll
        for (int u = 0; u < 4; ++u) {
            if (((const float*)&v)[u] != 0.0f) {
                int j = sinv[lt * 4 + u];
                if (j >= 0)
                    atomicOr(&bits[il * 17 + (j >> 5)], 1u << (j & 31));
            }
        }
        il = iln; pi = pin; v = vn;
    }
    __syncthreads();
    // dump: bm[b*8192 + w*512 + chunk*128 + il] = bits[il*17 + w]
    for (int idx = t; idx < 2048; idx += 1024) {
        int dil = idx & 127, w = idx >> 7;
        bm[(size_t)b * 8192 + w * 512 + chunk * 128 + dil] = bits[dil * 17 + w];
    }
}

// K5: adj_pooled[b,i,j] = (fw(i,j) | trans(j,i)) + (i==j).
// 8 blocks/graph x 64 output rows, 1024 threads (16 waves — full write BW).
// Stage whole 32 KB graph bitmap (col-major) in LDS; fw words to padded slab.
__global__ __launch_bounds__(1024) void adj_write_kernel(
    const unsigned* __restrict__ bm, float* __restrict__ out)
{
    __shared__ unsigned cb[16 * 512];       // 32 KB, cb[w*512 + j]
    __shared__ unsigned fws[64 * 17];       // 4.25 KB padded fw slab
    const int b = blockIdx.x >> 3;
    const int slab = blockIdx.x & 7;        // rows slab*64 .. +63
    const int t = threadIdx.x;
    const uint4* src = (const uint4*)(bm + (size_t)b * 8192);
    for (int idx = t; idx < 2048; idx += 1024)
        *(uint4*)&cb[idx * 4] = src[idx];
    __syncthreads();
    if (t < 64 * 16) {
        int il = t & 63, wi = t >> 6;
        fws[il * 17 + wi] = cb[wi * 512 + slab * 64 + il];
    }
    __syncthreads();

    float* ob = out + ((size_t)b * NK + slab * 64) * NK;
    #pragma unroll
    for (int it = 0; it < 8; ++it) {
        int lid = it * 1024 + t;            // < 8192
        int i_loc = lid >> 7;               // 0..63
        int i = slab * 64 + i_loc;
        int j4 = (lid & 127) * 4;
        unsigned fw = fws[i_loc * 17 + (j4 >> 5)];
        uint4 tq = *(const uint4*)&cb[(i >> 5) * 512 + j4];
        float4 res;
        float* rp = (float*)&res;
        const unsigned* tp = (const unsigned*)&tq;
        #pragma unroll
        for (int e = 0; e < 4; ++e) {
            unsigned bit = ((fw >> ((j4 + e) & 31)) | (tp[e] >> (i & 31))) & 1u;
            float f = (float)bit;
            if (i == j4 + e) f += 1.0f;
            rp[e] = f;
        }
        *(float4*)(ob + (size_t)i_loc * NK + j4) = res;
    }
}

extern "C" void kernel_launch(void* const* d_in, const int* in_sizes, int n_in,
                              void* d_out, int out_size, void* d_ws, size_t ws_size,
                              hipStream_t stream) {
    const float* x   = (const float*)d_in[0];
    const float* adj = (const float*)d_in[1];
    const float* w   = (const float*)d_in[2];
    float* out = (float*)d_out;

    char* p = (char*)d_ws;
    double*   sacc = (double*)p;    p += sizeof(double) * NB * NN;        // 512 KB
    unsigned* bm   = (unsigned*)p;  p += sizeof(unsigned) * NB * 16 * NK; // 2 MB
    int*      perm = (int*)p;       p += sizeof(int) * NB * NK;           // 128 KB
    float*    gate = (float*)p;     p += sizeof(float) * NB * NK;         // 128 KB
    int*      inv  = (int*)p;                                             // 256 KB

    float* x_pool     = out;                           // NB*NK*NC
    float* adj_pooled = out + (size_t)NB * NK * NC;    // NB*NK*NK

    score_kernel<<<NB * NN / 4, 256, 0, stream>>>(x, w, sacc);
    rank_kernel<<<NB * 4, 256, 0, stream>>>(sacc, w, perm, gate, inv);
    xpool_kernel<<<(NB * NK * NC / 4) / 256, 256, 0, stream>>>(x, perm, gate, x_pool);
    adj_scan_kernel<<<NB * 4, 1024, 0, stream>>>(adj, perm, inv, bm);
    adj_write_kernel<<<NB * 8, 1024, 0, stream>>>(bm, adj_pooled);
}

// Round 7
// 85.999 us; speedup vs baseline: 1.2636x; 1.1198x over previous
//
#include <hip/hip_runtime.h>
#include <math.h>

#define NB 64
#define NN 1024
#define NC 128
#define NK 512

// K1: fp64 dot(x[row,:], w) — 16 lanes per row (8 cols each), 4 rows/wave.
// Reduce = 4 shfl_xor stages within 16-lane groups (cheap vs 6-stage fly).
__global__ __launch_bounds__(256) void score_kernel(
    const float* __restrict__ x, const float* __restrict__ w,
    double* __restrict__ sacc)
{
    const int wv   = threadIdx.x >> 6;
    const int lane = threadIdx.x & 63;
    const int row  = blockIdx.x * 16 + wv * 4 + (lane >> 4);
    const int c0   = (lane & 15) * 8;
    const float4 a  = *(const float4*)(x + (size_t)row * NC + c0);
    const float4 b  = *(const float4*)(x + (size_t)row * NC + c0 + 4);
    const float4 wa = *(const float4*)(w + c0);
    const float4 wb = *(const float4*)(w + c0 + 4);
    double acc = (double)a.x * wa.x + (double)a.y * wa.y
               + (double)a.z * wa.z + (double)a.w * wa.w
               + (double)b.x * wb.x + (double)b.y * wb.y
               + (double)b.z * wb.z + (double)b.w * wb.w;
    acc += __shfl_xor(acc, 1, 64);
    acc += __shfl_xor(acc, 2, 64);
    acc += __shfl_xor(acc, 4, 64);
    acc += __shfl_xor(acc, 8, 64);
    if ((lane & 15) == 0) sacc[row] = acc;
}

// K2: exact rank-sort top-k on pre-tanh scores (monotone => same order as ref).
__global__ __launch_bounds__(256) void rank_kernel(
    const double* __restrict__ sacc, const float* __restrict__ w,
    int* __restrict__ perm, float* __restrict__ gate, int* __restrict__ inv)
{
    __shared__ double s[NN];
    __shared__ double s_rnw;
    const int b = blockIdx.x >> 2;
    const int q = blockIdx.x & 3;
    const int t = threadIdx.x;
    for (int idx = t; idx < NN; idx += 256)
        s[idx] = sacc[(size_t)b * NN + idx];
    if (t < 64) {
        double p = (double)w[t] * (double)w[t]
                 + (double)w[t + 64] * (double)w[t + 64];
        #pragma unroll
        for (int off = 32; off > 0; off >>= 1)
            p += __shfl_xor(p, off, 64);
        if (t == 0) s_rnw = 1.0 / sqrt(p);
    }
    __syncthreads();

    const int n = q * 256 + t;
    const double my = s[n];
    int r = 0;
    #pragma unroll 8
    for (int j = 0; j < NN; ++j) {
        double o = s[j];
        r += (o > my) || ((o == my) && (j < n));
    }
    inv[b * NN + n] = (r < NK) ? r : -1;
    if (r < NK) {
        perm[b * NK + r] = n;
        gate[b * NK + r] = (float)tanh(my * s_rnw);
    }
}

// K3: fused scan (blocks 0..255) + xpool (blocks 256..1279), 1024 threads.
// Scan: 4 blocks/graph, 128 pooled rows each, 2-deep row prefetch; forward
// bits only into LDS [128][17]; dump COL-MAJOR to bm[b][w][j].
__global__ __launch_bounds__(1024) void scan_xpool_kernel(
    const float* __restrict__ adj, const int* __restrict__ perm,
    const int* __restrict__ inv, const float* __restrict__ gate,
    const float* __restrict__ x, unsigned* __restrict__ bm,
    float* __restrict__ x_pool)
{
    __shared__ unsigned bits[128 * 17];   // 8.5 KB
    __shared__ int sinv[NN];              // 4 KB
    if (blockIdx.x >= 256) {
        // ---- xpool role: x_pool[bi][c] = x[b][perm[bi]][c] * gate[bi]
        int id = (blockIdx.x - 256) * 1024 + threadIdx.x;  // < NB*NK*NC/4
        int c4 = id & (NC / 4 - 1);
        int bi = id >> 5;
        int b  = bi >> 9;
        int pi = perm[bi];
        float g = gate[bi];
        float4 v = *(const float4*)(x + ((size_t)b * NN + pi) * NC + c4 * 4);
        v.x *= g; v.y *= g; v.z *= g; v.w *= g;
        *(float4*)(x_pool + (size_t)id * 4) = v;
        return;
    }
    const int b = blockIdx.x >> 2;
    const int chunk = blockIdx.x & 3;
    const int t = threadIdx.x;
    for (int idx = t; idx < 128 * 17; idx += 1024) bits[idx] = 0;
    for (int idx = t; idx < NN; idx += 1024) sinv[idx] = inv[b * NN + idx];
    __syncthreads();

    const float* ab = adj + (size_t)b * NN * NN;
    const int* permb = perm + b * NK + chunk * 128;
    const int g  = t >> 8;               // local row-group 0..3
    const int lt = t & 255;

    int il = g;                          // rows g, g+4, ..., g+124
    float4 v0 = *(const float4*)(ab + (size_t)permb[il] * NN + lt * 4);
    float4 v1 = *(const float4*)(ab + (size_t)permb[il + 4] * NN + lt * 4);
    for (int it = 0; it < 32; ++it) {
        float4 vn = v0;
        if (it < 30)                     // 2-deep prefetch
            vn = *(const float4*)(ab + (size_t)permb[il + 8] * NN + lt * 4);
        #pragma unroll
        for (int u = 0; u < 4; ++u) {
            if (((const float*)&v0)[u] != 0.0f) {
                int j = sinv[lt * 4 + u];
                if (j >= 0)
                    atomicOr(&bits[il * 17 + (j >> 5)], 1u << (j & 31));
            }
        }
        v0 = v1; v1 = vn; il += 4;
    }
    __syncthreads();
    // dump: bm[b*8192 + w*512 + chunk*128 + dil] = bits[dil*17 + w]
    for (int idx = t; idx < 2048; idx += 1024) {
        int dil = idx & 127, w = idx >> 7;
        bm[(size_t)b * 8192 + w * 512 + chunk * 128 + dil] = bits[dil * 17 + w];
    }
}

// K4: adj_pooled[b,i,j] = (fw(i,j) | trans(j,i)) + (i==j).
// 8 blocks/graph x 64 output rows, 1024 threads. Stage ONLY the slab's
// needs: 2 trans word-cols (4 KB) + 64 fw rows into padded slab (4.25 KB).
__global__ __launch_bounds__(1024) void adj_write_kernel(
    const unsigned* __restrict__ bm, float* __restrict__ out)
{
    __shared__ unsigned tcb[2 * 512];       // trans word-cols slab*2, slab*2+1
    __shared__ unsigned fws[64 * 17];       // fw slab, padded
    const int b = blockIdx.x >> 3;
    const int slab = blockIdx.x & 7;        // rows slab*64 .. +63
    const int t = threadIdx.x;
    const unsigned* bmb = bm + (size_t)b * 8192;
    {   // trans: tcb[e*512 + j] = bmb[(slab*2+e)*512 + j]
        int e = t >> 9, j = t & 511;
        tcb[t] = bmb[(slab * 2 + e) * 512 + j];
    }
    if (t < 1024) {  // fw: fws[il*17+wi] = bmb[wi*512 + slab*64 + il]
        int il = t & 63, wi = t >> 6;
        fws[il * 17 + wi] = bmb[wi * 512 + slab * 64 + il];
    }
    __syncthreads();

    float* ob = out + ((size_t)b * NK + slab * 64) * NK;
    #pragma unroll
    for (int it = 0; it < 8; ++it) {
        int lid = it * 1024 + t;            // < 8192
        int i_loc = lid >> 7;               // 0..63
        int i = slab * 64 + i_loc;
        int j4 = (lid & 127) * 4;
        unsigned fw = fws[i_loc * 17 + (j4 >> 5)];
        uint4 tq = *(const uint4*)&tcb[(i_loc >> 5) * 512 + j4];
        float4 res;
        float* rp = (float*)&res;
        const unsigned* tp = (const unsigned*)&tq;
        #pragma unroll
        for (int e = 0; e < 4; ++e) {
            unsigned bit = ((fw >> ((j4 + e) & 31)) | (tp[e] >> (i & 31))) & 1u;
            float f = (float)bit;
            if (i == j4 + e) f += 1.0f;
            rp[e] = f;
        }
        *(float4*)(ob + (size_t)i_loc * NK + j4) = res;
    }
}

extern "C" void kernel_launch(void* const* d_in, const int* in_sizes, int n_in,
                              void* d_out, int out_size, void* d_ws, size_t ws_size,
                              hipStream_t stream) {
    const float* x   = (const float*)d_in[0];
    const float* adj = (const float*)d_in[1];
    const float* w   = (const float*)d_in[2];
    float* out = (float*)d_out;

    char* p = (char*)d_ws;
    double*   sacc = (double*)p;    p += sizeof(double) * NB * NN;        // 512 KB
    unsigned* bm   = (unsigned*)p;  p += sizeof(unsigned) * NB * 16 * NK; // 2 MB
    int*      perm = (int*)p;       p += sizeof(int) * NB * NK;           // 128 KB
    float*    gate = (float*)p;     p += sizeof(float) * NB * NK;         // 128 KB
    int*      inv  = (int*)p;                                             // 256 KB

    float* x_pool     = out;                           // NB*NK*NC
    float* adj_pooled = out + (size_t)NB * NK * NC;    // NB*NK*NK

    score_kernel<<<NB * NN / 16, 256, 0, stream>>>(x, w, sacc);
    rank_kernel<<<NB * 4, 256, 0, stream>>>(sacc, w, perm, gate, inv);
    scan_xpool_kernel<<<256 + NB * NK * NC / 4 / 1024, 1024, 0, stream>>>(
        adj, perm, inv, gate, x, bm, x_pool);
    adj_write_kernel<<<NB * 8, 1024, 0, stream>>>(bm, adj_pooled);
}